// Round 7
// baseline (328.319 us; speedup 1.0000x reference)
//
#include <hip/hip_runtime.h>

// MSPushPullLoss R7:
//  pass1 = R2's verified 65us structure: per-thread float2 [label][256] bins,
//          sequential RMW (race-free by thread-private column), + 2-deep prefetch.
//  pass2 = NO BINS: per-element pull contribution d^2 * invcnt via a 17-entry
//          (mean, inv_count) LDS table gather; single register accumulator per
//          thread; one global atomic per block. Background label -> inv=0.
// B=16, C=16, labels 0..16, seg = b*17+lab, NSEG=272.

#define NSEG 272
#define M_VAR 0.1f
#define TWO_M_DIST 3.0f
#define GRID_BLOCKS 1008   // scale0 16*48, scale1 16*12, scale2 16*3

__device__ __forceinline__ void gatomic_add(float* p, float v) {
  __hip_atomic_fetch_add(p, v, __ATOMIC_RELAXED, __HIP_MEMORY_SCOPE_AGENT);
}

struct Sel { const float4* f; const int4* g; int w, wend, stride, scale, batch; };

__device__ __forceinline__ Sel pick(
    int b, int t,
    const float4* f0, const int4* g0,
    const float4* f1, const int4* g1,
    const float4* f2, const int4* g2) {
  Sel s;
  if (b < 768) {
    int batch = b / 48, sub = b - batch * 48;
    s.f = f0; s.g = g0; s.scale = 0; s.batch = batch;
    s.w = batch * 262144 + sub * 256 + t; s.wend = (batch + 1) * 262144; s.stride = 48 * 256;
  } else if (b < 960) {
    int lb = b - 768, batch = lb / 12, sub = lb - batch * 12;
    s.f = f1; s.g = g1; s.scale = 1; s.batch = batch;
    s.w = batch * 65536 + sub * 256 + t; s.wend = (batch + 1) * 65536; s.stride = 12 * 256;
  } else {
    int lb = b - 960, batch = lb / 3, sub = lb - batch * 3;
    s.f = f2; s.g = g2; s.scale = 2; s.batch = batch;
    s.w = batch * 16384 + sub * 256 + t; s.wend = (batch + 1) * 16384; s.stride = 3 * 256;
  }
  return s;
}

// ---------------- pass 1: per-(batch,label) sums + per-(scale,batch,label) counts ----------------
__global__ __launch_bounds__(256, 4) void pass1_kernel(
    const float4* __restrict__ f0, const int4* __restrict__ g0,
    const float4* __restrict__ f1, const int4* __restrict__ g1,
    const float4* __restrict__ f2, const int4* __restrict__ g2,
    float* __restrict__ tot_sum,   // [NSEG]
    float* __restrict__ cnt)       // [3][NSEG]
{
  __shared__ float2 bins[17 * 256];   // [label][thread] {sum,count} -- 34816 B
  const int t = threadIdx.x;
  for (int i = t; i < 17 * 256; i += 256) bins[i] = make_float2(0.f, 0.f);
  __syncthreads();

  Sel s = pick(blockIdx.x, t, f0, g0, f1, g1, f2, g2);

  auto rmw = [&](float fv, int gv) {
    int idx = (int)min((unsigned)gv, 16u) * 256 + t;  // label 0 bin never read
    float2 r = bins[idx];
    bins[idx] = make_float2(r.x + fv, r.y + 1.f);
  };

  // 2-deep prefetch
  int st = s.stride;
  int v = s.w;
  bool h0 = v < s.wend, h1 = (v + st) < s.wend;
  float4 Fa, Fb; int4 Ga, Gb;
  if (h0) { Fa = s.f[v]; Ga = s.g[v]; }
  if (h1) { Fb = s.f[v + st]; Gb = s.g[v + st]; }
  while (h0) {
    int vp = v + 2 * st; bool hp = vp < s.wend;
    float4 Fc; int4 Gc;
    if (hp) { Fc = s.f[vp]; Gc = s.g[vp]; }
    rmw(Fa.x, Ga.x); rmw(Fa.y, Ga.y); rmw(Fa.z, Ga.z); rmw(Fa.w, Ga.w);
    v += st; h0 = h1; h1 = hp;
    Fa = Fb; Ga = Gb; Fb = Fc; Gb = Gc;
  }

  // tree-reduce over thread dim: [17][256] -> [17][1]
  for (int sh = 7; sh >= 0; --sh) {
    __syncthreads();
    int off = 1 << sh;
    for (int i = t; i < 17 * off; i += 256) {
      int l = i >> sh, tt = i & (off - 1);
      int a = l * 256 + tt;
      float2 x = bins[a], y = bins[a + off];
      bins[a] = make_float2(x.x + y.x, x.y + y.y);
    }
  }
  __syncthreads();

  if (t >= 1 && t < 17) {
    float2 r = bins[t * 256];
    if (r.y != 0.f) {
      gatomic_add(&tot_sum[s.batch * 17 + t], r.x);
      gatomic_add(&cnt[s.scale * NSEG + s.batch * 17 + t], r.y);
    }
  }
}

// ---------------- pass 2: table-gather, register accumulator, last-block finalize ----------------
__global__ __launch_bounds__(256, 4) void pass2_kernel(
    const float4* __restrict__ f0, const int4* __restrict__ g0,
    const float4* __restrict__ f1, const int4* __restrict__ g1,
    const float4* __restrict__ f2, const int4* __restrict__ g2,
    const float* __restrict__ tot_sum,  // [NSEG]
    const float* __restrict__ cnt,      // [3][NSEG]
    float* __restrict__ pull_total,     // [1]
    int* __restrict__ counter,
    float* __restrict__ out)
{
  __shared__ float2 s_tab[17];   // {mean, inv per-scale count (0 if bg/absent)}
  const int t = threadIdx.x;
  Sel s = pick(blockIdx.x, t, f0, g0, f1, g1, f2, g2);

  if (t < 17) {
    int seg = s.batch * 17 + t;
    float c = cnt[seg] + cnt[NSEG + seg] + cnt[2 * NSEG + seg];
    float m = tot_sum[seg] / fmaxf(c, 1.f);
    float cs = cnt[s.scale * NSEG + seg];
    float inv = (t >= 1 && cs > 0.f) ? 1.f / cs : 0.f;  // label 0 -> 0
    s_tab[t] = make_float2(m, inv);
  }
  __syncthreads();

  float acc = 0.f;
  auto body = [&](float f, int g) {
    float2 tr = s_tab[min((unsigned)g, 16u)];   // b64 gather, <=17 addrs, distinct banks
    float d = fmaxf(fabsf(f - tr.x) - M_VAR, 0.f);
    acc = fmaf(d * d, tr.y, acc);
  };

  int st = s.stride;
  int v = s.w;
  bool h0 = v < s.wend, h1 = (v + st) < s.wend;
  float4 Fa, Fb; int4 Ga, Gb;
  if (h0) { Fa = s.f[v]; Ga = s.g[v]; }
  if (h1) { Fb = s.f[v + st]; Gb = s.g[v + st]; }
  while (h0) {
    int vp = v + 2 * st; bool hp = vp < s.wend;
    float4 Fc; int4 Gc;
    if (hp) { Fc = s.f[vp]; Gc = s.g[vp]; }
    body(Fa.x, Ga.x); body(Fa.y, Ga.y); body(Fa.z, Ga.z); body(Fa.w, Ga.w);
    v += st; h0 = h1; h1 = hp;
    Fa = Fb; Ga = Gb; Fb = Fc; Gb = Gc;
  }

  // reduce acc across block, one global atomic
  #pragma unroll
  for (int o = 32; o > 0; o >>= 1) acc += __shfl_down(acc, o);
  __shared__ float rblk[4];
  int wave = t >> 6, lane = t & 63;
  if (lane == 0) rblk[wave] = acc;
  __syncthreads();
  if (t == 0) {
    float a = rblk[0] + rblk[1] + rblk[2] + rblk[3];
    if (a != 0.f) gatomic_add(pull_total, a);
  }

  // ---- completion ticket; last block finalizes ----
  __threadfence();
  __shared__ int is_last;
  if (t == 0) {
    int ticket = __hip_atomic_fetch_add(counter, 1, __ATOMIC_ACQ_REL, __HIP_MEMORY_SCOPE_AGENT);
    is_last = (ticket == GRID_BLOCKS - 1) ? 1 : 0;
  }
  __syncthreads();
  if (!is_last) return;
  __threadfence();

  __shared__ float fz_mean[NSEG];
  __shared__ unsigned char fz_pres[NSEG];
  for (int i = t; i < NSEG; i += 256) {
    float c = cnt[i] + cnt[NSEG + i] + cnt[2 * NSEG + i];
    fz_pres[i] = (c > 0.f) ? 1 : 0;
    fz_mean[i] = tot_sum[i] / fmaxf(c, 1.f);
  }
  __syncthreads();

  float pull_n = 0.f, push_v = 0.f, push_n = 0.f;
  for (int i = t; i < NSEG; i += 256) {
    int lab = i - (i / 17) * 17;
    if (lab >= 1 && fz_pres[i]) pull_n += 1.f;
  }
  {
    int b = t >> 4, ii = t & 15;
    int si = b * 17 + ii + 1;
    if (fz_pres[si]) {
      float mi = fz_mean[si];
      for (int j = 0; j < 16; ++j) {
        if (j == ii) continue;
        int sj = b * 17 + j + 1;
        if (fz_pres[sj]) {
          float d = fmaxf(TWO_M_DIST - fabsf(mi - fz_mean[sj]), 0.f);
          push_v += d * d;
          push_n += 1.f;
        }
      }
    }
  }

  #pragma unroll
  for (int o = 32; o > 0; o >>= 1) {
    pull_n += __shfl_down(pull_n, o);
    push_v += __shfl_down(push_v, o);
    push_n += __shfl_down(push_n, o);
  }
  __shared__ float r[4][3];
  if (lane == 0) { r[wave][0] = pull_n; r[wave][1] = push_v; r[wave][2] = push_n; }
  __syncthreads();
  if (t == 0) {
    float PN = 0, SV = 0, SN = 0;
    for (int w = 0; w < 4; ++w) { PN += r[w][0]; SV += r[w][1]; SN += r[w][2]; }
    float pv = __hip_atomic_load(pull_total, __ATOMIC_RELAXED, __HIP_MEMORY_SCOPE_AGENT);
    out[0] = pv / fmaxf(PN, 1.f) + SV / fmaxf(SN, 1.f);
  }
}

extern "C" void kernel_launch(void* const* d_in, const int* in_sizes, int n_in,
                              void* d_out, int out_size, void* d_ws, size_t ws_size,
                              hipStream_t stream) {
  // setup_inputs() dict order: featmap0, gt0, featmap1, gt1, featmap2, gt2
  const float4* f0 = (const float4*)d_in[0];
  const int4*   g0 = (const int4*)  d_in[1];
  const float4* f1 = (const float4*)d_in[2];
  const int4*   g1 = (const int4*)  d_in[3];
  const float4* f2 = (const float4*)d_in[4];
  const int4*   g2 = (const int4*)  d_in[5];

  float* ws         = (float*)d_ws;
  float* tot_sum    = ws;                 // [NSEG]
  float* cnt        = ws + NSEG;          // [3][NSEG]
  float* pull_total = ws + 4 * NSEG;      // [1]
  int*   counter    = (int*)(ws + 4 * NSEG + 1);

  hipMemsetAsync(d_ws, 0, (4 * NSEG + 2) * sizeof(float), stream);
  pass1_kernel<<<GRID_BLOCKS, 256, 0, stream>>>(f0, g0, f1, g1, f2, g2, tot_sum, cnt);
  pass2_kernel<<<GRID_BLOCKS, 256, 0, stream>>>(f0, g0, f1, g1, f2, g2, tot_sum, cnt,
                                                pull_total, counter, (float*)d_out);
}